// Round 1
// baseline (598.148 us; speedup 1.0000x reference)
//
#include <hip/hip_runtime.h>

typedef unsigned short u16;
typedef __attribute__((ext_vector_type(8))) short bf16x8;
typedef __attribute__((ext_vector_type(4))) float f32x4;

#define NV 65
#define ND 64
#define NT 32
#define NL 4
#define NH 4
#define NFF 256
#define NSEQ 8192
#define NTOK (NSEQ * NT)

// ws layout (u16 elements)
#define WQT_OFF 0
#define WKT_OFF 16384
#define WVT_OFF 32768
#define WOT_OFF 49152
#define W1T_OFF 65536
#define W2T_OFF 131072
#define WHT_OFF 196608
#define WS_U16_TOTAL 201728
#define LOSS_BYTE_OFF (WS_U16_TOTAL * 2)

__device__ __forceinline__ u16 f2bf(float f) {
  union { float f; unsigned u; } c; c.f = f;
  return (u16)((c.u + 0x7FFFu + ((c.u >> 16) & 1u)) >> 16);
}
__device__ __forceinline__ float bf2f(u16 h) {
  union { unsigned u; float f; } c; c.u = ((unsigned)h) << 16;
  return c.f;
}
__device__ __forceinline__ f32x4 zero4() {
  f32x4 z; z[0] = 0.f; z[1] = 0.f; z[2] = 0.f; z[3] = 0.f; return z;
}

// ---------------- prep: weights -> bf16, transposed to [N][K] ----------------
__global__ void prep_kernel(const float* __restrict__ Wq, const float* __restrict__ Wk,
                            const float* __restrict__ Wv, const float* __restrict__ Wo,
                            const float* __restrict__ W1, const float* __restrict__ W2,
                            const float* __restrict__ Wh, u16* __restrict__ ws,
                            float* __restrict__ loss_acc) {
  int i = blockIdx.x * 256 + threadIdx.x;
  if (i == 0) *loss_acc = 0.f;
  if (i < 16384) {  // Wq/Wk/Wv/Wo: [L][64][64] -> T[L][n][k]
    int lay = i >> 12, j = i & 4095, n = j >> 6, k = j & 63;
    int src = (lay << 12) + (k << 6) + n;
    ws[WQT_OFF + i] = f2bf(Wq[src]);
    ws[WKT_OFF + i] = f2bf(Wk[src]);
    ws[WVT_OFF + i] = f2bf(Wv[src]);
    ws[WOT_OFF + i] = f2bf(Wo[src]);
  }
  if (i < 65536) {
    int lay = i >> 14, j = i & 16383;
    { int n = j >> 6, k = j & 63;   ws[W1T_OFF + i] = f2bf(W1[(lay << 14) + (k << 8) + n]); }
    { int n = j >> 8, k = j & 255;  ws[W2T_OFF + i] = f2bf(W2[(lay << 14) + (k << 6) + n]); }
  }
  if (i < 5120) {  // WhT [80][64], rows >= 65 zero
    int n = i >> 6, k = i & 63;
    ws[WHT_OFF + i] = (n < NV) ? f2bf(Wh[k * NV + n]) : (u16)0;
  }
}

// ---------------- LayerNorm helper (one wave, rows in LDS) ----------------
__device__ __forceinline__ void layer_norm(const u16 (*src)[72], u16 (*dst)[72],
                                           const float* __restrict__ g, const float* __restrict__ b,
                                           float* mu_s, float* rs_s, int l) {
  int r = l >> 1, c0 = (l & 1) * 32;
  float s = 0.f, sq = 0.f;
#pragma unroll
  for (int c8 = 0; c8 < 4; ++c8) {
    bf16x8 v8 = *(const bf16x8*)&src[r][c0 + c8 * 8];
#pragma unroll
    for (int j = 0; j < 8; ++j) {
      float v = bf2f((u16)v8[j]);
      s += v; sq += v * v;
    }
  }
  s += __shfl_xor(s, 1); sq += __shfl_xor(sq, 1);
  if (!(l & 1)) {
    float mu = s * (1.f / 64.f);
    float var = sq * (1.f / 64.f) - mu * mu;
    mu_s[r] = mu;
    rs_s[r] = rsqrtf(var + 1e-5f);
  }
  __syncthreads();
  float ga = g[l], be = b[l];
#pragma unroll 4
  for (int rr = 0; rr < NT; ++rr) {
    float v = bf2f(src[rr][l]);
    dst[rr][l] = f2bf((v - mu_s[rr]) * rs_s[rr] * ga + be);
  }
  __syncthreads();
}

// ---------------- fused forward: one wave per sequence ----------------
__global__ __launch_bounds__(64) void fwd_kernel(
    const int* __restrict__ idx, const int* __restrict__ tgt,
    const float* __restrict__ tok_emb, const float* __restrict__ pos_emb,
    const float* __restrict__ bo, const float* __restrict__ ln1g, const float* __restrict__ ln1b,
    const float* __restrict__ ln2g, const float* __restrict__ ln2b,
    const float* __restrict__ b1, const float* __restrict__ b2,
    const float* __restrict__ lnfg, const float* __restrict__ lnfb, const float* __restrict__ bh,
    const u16* __restrict__ ws, float* __restrict__ out, float* __restrict__ loss_acc) {
  __shared__ u16 xs[NT][72];   // residual (bf16), stride 144B (16B aligned rows)
  __shared__ u16 ls[NT][72];   // LN output
  __shared__ u16 tp[NT][72];   // attn-out / FFN h1 chunk
  __shared__ u16 qp[NT][40];   // q (cols 0..15; 16..31 zero K-pad), then P (cols 0..31)
  __shared__ u16 kh[NT][40];   // k (cols 16..31 permanently zero)
  __shared__ u16 vt[16][40];   // v transposed [dim][key]
  __shared__ float mu_s[NT];
  __shared__ float rs_s[NT];

  const int l = threadIdx.x;
  const int m = l & 15, g = l >> 4;
  const int seq = blockIdx.x;
  const int row_g = 4 * g;

  // zero permanent K-pad of kh
  {
    int r = l >> 1, c0 = 16 + (l & 1) * 8;
#pragma unroll
    for (int c = 0; c < 8; ++c) kh[r][c0 + c] = 0;
  }
  // embedding: x = tok_emb[idx] + pos_emb
  const int* idxp = idx + seq * NT;
#pragma unroll 4
  for (int r = 0; r < NT; ++r) {
    int t = idxp[r];
    xs[r][l] = f2bf(tok_emb[t * ND + l] + pos_emb[r * ND + l]);
  }
  __syncthreads();

  for (int lay = 0; lay < NL; ++lay) {
    const u16* wq = ws + WQT_OFF + lay * 4096;
    const u16* wk = ws + WKT_OFF + lay * 4096;
    const u16* wv = ws + WVT_OFF + lay * 4096;
    const u16* wo = ws + WOT_OFF + lay * 4096;
    const u16* w1 = ws + W1T_OFF + lay * 16384;
    const u16* w2 = ws + W2T_OFF + lay * 16384;

    layer_norm(xs, ls, ln1g + lay * ND, ln1b + lay * ND, mu_s, rs_s, l);

    // A-fragments of ls, reused across heads
    bf16x8 a_ls[2][2];
#pragma unroll
    for (int mt = 0; mt < 2; ++mt)
#pragma unroll
      for (int ks = 0; ks < 2; ++ks)
        a_ls[mt][ks] = *(const bf16x8*)&ls[16 * mt + m][32 * ks + 8 * g];

    for (int h = 0; h < NH; ++h) {
      // ---- QKV for this head (N = 16 cols of each weight) ----
      f32x4 qa[2], ka[2], va[2];
#pragma unroll
      for (int mt = 0; mt < 2; ++mt) { qa[mt] = zero4(); ka[mt] = zero4(); va[mt] = zero4(); }
#pragma unroll
      for (int ks = 0; ks < 2; ++ks) {
        int wrow = (16 * h + m) * 64 + 32 * ks + 8 * g;
        bf16x8 bq = *(const bf16x8*)&wq[wrow];
        bf16x8 bk = *(const bf16x8*)&wk[wrow];
        bf16x8 bv = *(const bf16x8*)&wv[wrow];
#pragma unroll
        for (int mt = 0; mt < 2; ++mt) {
          qa[mt] = __builtin_amdgcn_mfma_f32_16x16x32_bf16(a_ls[mt][ks], bq, qa[mt], 0, 0, 0);
          ka[mt] = __builtin_amdgcn_mfma_f32_16x16x32_bf16(a_ls[mt][ks], bk, ka[mt], 0, 0, 0);
          va[mt] = __builtin_amdgcn_mfma_f32_16x16x32_bf16(a_ls[mt][ks], bv, va[mt], 0, 0, 0);
        }
      }
      __syncthreads();  // previous head fully done with qp/vt
#pragma unroll
      for (int mt = 0; mt < 2; ++mt)
#pragma unroll
        for (int r = 0; r < 4; ++r) {
          int tok = 16 * mt + row_g + r;
          qp[tok][m] = f2bf(qa[mt][r]);
          qp[tok][16 + m] = 0;  // restore K-pad zeros (clobbered by last head's P)
          kh[tok][m] = f2bf(ka[mt][r]);
          vt[m][tok] = f2bf(va[mt][r]);
        }
      __syncthreads();
      // ---- scores = q @ k^T (K padded 16->32 with zeros) ----
      f32x4 sc[2][2];
#pragma unroll
      for (int mt = 0; mt < 2; ++mt) { sc[mt][0] = zero4(); sc[mt][1] = zero4(); }
      bf16x8 bk0 = *(const bf16x8*)&kh[m][8 * g];
      bf16x8 bk1 = *(const bf16x8*)&kh[16 + m][8 * g];
#pragma unroll
      for (int mt = 0; mt < 2; ++mt) {
        bf16x8 aq = *(const bf16x8*)&qp[16 * mt + m][8 * g];
        sc[mt][0] = __builtin_amdgcn_mfma_f32_16x16x32_bf16(aq, bk0, sc[mt][0], 0, 0, 0);
        sc[mt][1] = __builtin_amdgcn_mfma_f32_16x16x32_bf16(aq, bk1, sc[mt][1], 0, 0, 0);
      }
      // ---- causal softmax (scale = D^-0.5 = 0.125), P -> qp cols 0..31 ----
#pragma unroll
      for (int mt = 0; mt < 2; ++mt)
#pragma unroll
        for (int r = 0; r < 4; ++r) {
          int tok = 16 * mt + row_g + r;
          float s0 = sc[mt][0][r] * 0.125f; if (m > tok) s0 = -1e30f;
          float s1 = sc[mt][1][r] * 0.125f; if (16 + m > tok) s1 = -1e30f;
          float mx = fmaxf(s0, s1);
          mx = fmaxf(mx, __shfl_xor(mx, 1));
          mx = fmaxf(mx, __shfl_xor(mx, 2));
          mx = fmaxf(mx, __shfl_xor(mx, 4));
          mx = fmaxf(mx, __shfl_xor(mx, 8));
          float e0 = __expf(s0 - mx), e1 = __expf(s1 - mx);
          float sm = e0 + e1;
          sm += __shfl_xor(sm, 1); sm += __shfl_xor(sm, 2);
          sm += __shfl_xor(sm, 4); sm += __shfl_xor(sm, 8);
          float inv = 1.f / sm;
          qp[tok][m] = f2bf(e0 * inv);
          qp[tok][16 + m] = f2bf(e1 * inv);
        }
      __syncthreads();
      // ---- out_h = P @ v ----
      bf16x8 bv2 = *(const bf16x8*)&vt[m][8 * g];
#pragma unroll
      for (int mt = 0; mt < 2; ++mt) {
        bf16x8 ap = *(const bf16x8*)&qp[16 * mt + m][8 * g];
        f32x4 o = zero4();
        o = __builtin_amdgcn_mfma_f32_16x16x32_bf16(ap, bv2, o, 0, 0, 0);
#pragma unroll
        for (int r = 0; r < 4; ++r)
          tp[16 * mt + row_g + r][16 * h + m] = f2bf(o[r]);
      }
    }
    __syncthreads();
    // ---- Wo projection + bias + residual ----
    {
      f32x4 acc[2][4];
#pragma unroll
      for (int mt = 0; mt < 2; ++mt)
#pragma unroll
        for (int nt = 0; nt < 4; ++nt) acc[mt][nt] = zero4();
      bf16x8 a_t[2][2];
#pragma unroll
      for (int mt = 0; mt < 2; ++mt)
#pragma unroll
        for (int ks = 0; ks < 2; ++ks)
          a_t[mt][ks] = *(const bf16x8*)&tp[16 * mt + m][32 * ks + 8 * g];
#pragma unroll
      for (int ks = 0; ks < 2; ++ks)
#pragma unroll
        for (int nt = 0; nt < 4; ++nt) {
          bf16x8 bw = *(const bf16x8*)&wo[(16 * nt + m) * 64 + 32 * ks + 8 * g];
#pragma unroll
          for (int mt = 0; mt < 2; ++mt)
            acc[mt][nt] = __builtin_amdgcn_mfma_f32_16x16x32_bf16(a_t[mt][ks], bw, acc[mt][nt], 0, 0, 0);
        }
#pragma unroll
      for (int nt = 0; nt < 4; ++nt) {
        float bon = bo[lay * ND + 16 * nt + m];
#pragma unroll
        for (int mt = 0; mt < 2; ++mt)
#pragma unroll
          for (int r = 0; r < 4; ++r) {
            int tok = 16 * mt + row_g + r, col = 16 * nt + m;
            xs[tok][col] = f2bf(acc[mt][nt][r] + bon + bf2f(xs[tok][col]));
          }
      }
    }
    __syncthreads();
    layer_norm(xs, ls, ln2g + lay * ND, ln2b + lay * ND, mu_s, rs_s, l);
    // ---- FFN in 4 chunks of 64 ----
    {
      bf16x8 a_l2[2][2];
#pragma unroll
      for (int mt = 0; mt < 2; ++mt)
#pragma unroll
        for (int ks = 0; ks < 2; ++ks)
          a_l2[mt][ks] = *(const bf16x8*)&ls[16 * mt + m][32 * ks + 8 * g];
      f32x4 acc2[2][4];
#pragma unroll
      for (int mt = 0; mt < 2; ++mt)
#pragma unroll
        for (int nt = 0; nt < 4; ++nt) acc2[mt][nt] = zero4();
      for (int c = 0; c < 4; ++c) {
        f32x4 hc[2][4];
#pragma unroll
        for (int mt = 0; mt < 2; ++mt)
#pragma unroll
          for (int nt = 0; nt < 4; ++nt) hc[mt][nt] = zero4();
#pragma unroll
        for (int ks = 0; ks < 2; ++ks)
#pragma unroll
          for (int nt = 0; nt < 4; ++nt) {
            bf16x8 bw = *(const bf16x8*)&w1[(64 * c + 16 * nt + m) * 64 + 32 * ks + 8 * g];
#pragma unroll
            for (int mt = 0; mt < 2; ++mt)
              hc[mt][nt] = __builtin_amdgcn_mfma_f32_16x16x32_bf16(a_l2[mt][ks], bw, hc[mt][nt], 0, 0, 0);
          }
        __syncthreads();  // previous chunk's tp reads complete
#pragma unroll
        for (int nt = 0; nt < 4; ++nt) {
          float b1n = b1[lay * NFF + 64 * c + 16 * nt + m];
#pragma unroll
          for (int mt = 0; mt < 2; ++mt)
#pragma unroll
            for (int r = 0; r < 4; ++r)
              tp[16 * mt + row_g + r][16 * nt + m] = f2bf(fmaxf(hc[mt][nt][r] + b1n, 0.f));
        }
        __syncthreads();
        bf16x8 a_h[2][2];
#pragma unroll
        for (int mt = 0; mt < 2; ++mt)
#pragma unroll
          for (int ks = 0; ks < 2; ++ks)
            a_h[mt][ks] = *(const bf16x8*)&tp[16 * mt + m][32 * ks + 8 * g];
#pragma unroll
        for (int ks = 0; ks < 2; ++ks)
#pragma unroll
          for (int nt = 0; nt < 4; ++nt) {
            bf16x8 bw = *(const bf16x8*)&w2[(16 * nt + m) * NFF + 64 * c + 32 * ks + 8 * g];
#pragma unroll
            for (int mt = 0; mt < 2; ++mt)
              acc2[mt][nt] = __builtin_amdgcn_mfma_f32_16x16x32_bf16(a_h[mt][ks], bw, acc2[mt][nt], 0, 0, 0);
          }
      }
#pragma unroll
      for (int nt = 0; nt < 4; ++nt) {
        float b2n = b2[lay * ND + 16 * nt + m];
#pragma unroll
        for (int mt = 0; mt < 2; ++mt)
#pragma unroll
          for (int r = 0; r < 4; ++r) {
            int tok = 16 * mt + row_g + r, col = 16 * nt + m;
            xs[tok][col] = f2bf(acc2[mt][nt][r] + b2n + bf2f(xs[tok][col]));
          }
      }
    }
    __syncthreads();
  }

  // ---- final LN + head + logits + loss ----
  layer_norm(xs, ls, lnfg, lnfb, mu_s, rs_s, l);
  bf16x8 a_f[2][2];
#pragma unroll
  for (int mt = 0; mt < 2; ++mt)
#pragma unroll
    for (int ks = 0; ks < 2; ++ks)
      a_f[mt][ks] = *(const bf16x8*)&ls[16 * mt + m][32 * ks + 8 * g];
  f32x4 lg[2][5];
#pragma unroll
  for (int mt = 0; mt < 2; ++mt)
#pragma unroll
    for (int nt = 0; nt < 5; ++nt) lg[mt][nt] = zero4();
#pragma unroll
  for (int ks = 0; ks < 2; ++ks)
#pragma unroll
    for (int nt = 0; nt < 5; ++nt) {
      bf16x8 bw = *(const bf16x8*)&ws[WHT_OFF + (16 * nt + m) * 64 + 32 * ks + 8 * g];
#pragma unroll
      for (int mt = 0; mt < 2; ++mt)
        lg[mt][nt] = __builtin_amdgcn_mfma_f32_16x16x32_bf16(a_f[mt][ks], bw, lg[mt][nt], 0, 0, 0);
    }
  const int* tgp = tgt + seq * NT;
  float lloss = 0.f;
#pragma unroll
  for (int mt = 0; mt < 2; ++mt)
#pragma unroll
    for (int r = 0; r < 4; ++r) {
      int tok = 16 * mt + row_g + r;
      float val[5];
      float mx = -1e30f;
#pragma unroll
      for (int nt = 0; nt < 5; ++nt) {
        int cc = 16 * nt + m;
        float v = (cc < NV) ? (lg[mt][nt][r] + bh[cc < NV ? cc : 0]) : -1e30f;
        val[nt] = v;
        mx = fmaxf(mx, v);
      }
      mx = fmaxf(mx, __shfl_xor(mx, 1));
      mx = fmaxf(mx, __shfl_xor(mx, 2));
      mx = fmaxf(mx, __shfl_xor(mx, 4));
      mx = fmaxf(mx, __shfl_xor(mx, 8));
      float se = 0.f;
#pragma unroll
      for (int nt = 0; nt < 5; ++nt) se += __expf(val[nt] - mx);
      se += __shfl_xor(se, 1); se += __shfl_xor(se, 2);
      se += __shfl_xor(se, 4); se += __shfl_xor(se, 8);
      float lse = __logf(se) + mx;
      int t = tgp[tok];
      float tpv = 0.f;
#pragma unroll
      for (int nt = 0; nt < 5; ++nt) tpv += (16 * nt + m == t) ? val[nt] : 0.f;
      float tv = __shfl(tpv, 16 * g + (t & 15));
      if (m == 0) lloss += lse - tv;
      size_t obase = ((size_t)seq * NT + tok) * NV;
#pragma unroll
      for (int nt = 0; nt < 5; ++nt) {
        int cc = 16 * nt + m;
        if (cc < NV) out[obase + cc] = val[nt];
      }
    }
  lloss += __shfl_xor(lloss, 16);
  lloss += __shfl_xor(lloss, 32);
  if (l == 0) atomicAdd(loss_acc, lloss);
}

__global__ void finalize_kernel(const float* __restrict__ loss_acc, float* __restrict__ out) {
  if (threadIdx.x == 0 && blockIdx.x == 0)
    out[(size_t)NTOK * NV] = loss_acc[0] * (1.f / (float)NTOK);
}

extern "C" void kernel_launch(void* const* d_in, const int* in_sizes, int n_in,
                              void* d_out, int out_size, void* d_ws, size_t ws_size,
                              hipStream_t stream) {
  const int* idx = (const int*)d_in[0];
  const int* tgt = (const int*)d_in[1];
  const float* tok_emb = (const float*)d_in[2];
  const float* pos_emb = (const float*)d_in[3];
  const float* Wq = (const float*)d_in[4];
  const float* Wk = (const float*)d_in[5];
  const float* Wv = (const float*)d_in[6];
  const float* Wo = (const float*)d_in[7];
  const float* bo = (const float*)d_in[8];
  const float* ln1g = (const float*)d_in[9];
  const float* ln1b = (const float*)d_in[10];
  const float* ln2g = (const float*)d_in[11];
  const float* ln2b = (const float*)d_in[12];
  const float* W1 = (const float*)d_in[13];
  const float* b1 = (const float*)d_in[14];
  const float* W2 = (const float*)d_in[15];
  const float* b2 = (const float*)d_in[16];
  const float* lnfg = (const float*)d_in[17];
  const float* lnfb = (const float*)d_in[18];
  const float* Wh = (const float*)d_in[19];
  const float* bh = (const float*)d_in[20];
  u16* ws = (u16*)d_ws;
  float* loss_acc = (float*)((char*)d_ws + LOSS_BYTE_OFF);
  float* out = (float*)d_out;

  prep_kernel<<<256, 256, 0, stream>>>(Wq, Wk, Wv, Wo, W1, W2, Wh, ws, loss_acc);
  fwd_kernel<<<NSEQ, 64, 0, stream>>>(idx, tgt, tok_emb, pos_emb, bo, ln1g, ln1b, ln2g, ln2b,
                                      b1, b2, lnfg, lnfb, bh, ws, out, loss_acc);
  finalize_kernel<<<1, 64, 0, stream>>>(loss_acc, out);
}

// Round 2
// 556.568 us; speedup vs baseline: 1.0747x; 1.0747x over previous
//
#include <hip/hip_runtime.h>

typedef unsigned short u16;
typedef unsigned int u32;
typedef __attribute__((ext_vector_type(8))) short bf16x8;
typedef __attribute__((ext_vector_type(4))) float f32x4;
typedef __attribute__((ext_vector_type(2))) unsigned u32x2;

#define NV 65
#define ND 64
#define NT 32
#define NL 4
#define NH 4
#define NFF 256
#define NSEQ 8192
#define NTOK (NSEQ * NT)

// ws layout (u16 elements)
#define WQT_OFF 0
#define WKT_OFF 16384
#define WVT_OFF 32768
#define WOT_OFF 49152
#define W1T_OFF 65536
#define W2T_OFF 131072
#define WHT_OFF 196608
#define WS_U16_TOTAL 201728
#define LOSS_BYTE_OFF (WS_U16_TOTAL * 2)

#define MFMA(a, b, c) __builtin_amdgcn_mfma_f32_16x16x32_bf16(a, b, c, 0, 0, 0)

__device__ __forceinline__ u32 cvtpk(float lo, float hi) {
  u32 r;
  asm("v_cvt_pk_bf16_f32 %0, %1, %2" : "=v"(r) : "v"(lo), "v"(hi));
  return r;
}
__device__ __forceinline__ u16 f2bf(float f) { return (u16)cvtpk(f, f); }
__device__ __forceinline__ float asf(u32 u) { union { u32 u; float f; } c; c.u = u; return c.f; }
__device__ __forceinline__ float bf2f(u16 h) { return asf(((u32)h) << 16); }
__device__ __forceinline__ f32x4 zero4() {
  f32x4 z; z[0] = 0.f; z[1] = 0.f; z[2] = 0.f; z[3] = 0.f; return z;
}
template <int CTRL>
__device__ __forceinline__ float dpp_add(float x) {
  int yi = __builtin_amdgcn_update_dpp(0, __float_as_int(x), CTRL, 0xf, 0xf, true);
  return x + __int_as_float(yi);
}
// reduce over the 16-lane group (xor 1,2,4,8) via DPP
__device__ __forceinline__ float red16(float x) {
  x = dpp_add<0xB1>(x);   // quad_perm(1,0,3,2)  : xor 1
  x = dpp_add<0x4E>(x);   // quad_perm(2,3,0,1)  : xor 2
  x = dpp_add<0x141>(x);  // row_half_mirror     : xor 4
  x = dpp_add<0x140>(x);  // row_mirror          : xor 8
  return x;
}

// ---------------- prep: weights -> bf16, transposed to [N][K] ----------------
__global__ void prep_kernel(const float* __restrict__ Wq, const float* __restrict__ Wk,
                            const float* __restrict__ Wv, const float* __restrict__ Wo,
                            const float* __restrict__ W1, const float* __restrict__ W2,
                            const float* __restrict__ Wh, u16* __restrict__ ws,
                            float* __restrict__ loss_acc) {
  int i = blockIdx.x * 256 + threadIdx.x;
  if (i == 0) *loss_acc = 0.f;
  if (i < 16384) {
    int lay = i >> 12, j = i & 4095, n = j >> 6, k = j & 63;
    int src = (lay << 12) + (k << 6) + n;
    ws[WQT_OFF + i] = f2bf(Wq[src]);
    ws[WKT_OFF + i] = f2bf(Wk[src]);
    ws[WVT_OFF + i] = f2bf(Wv[src]);
    ws[WOT_OFF + i] = f2bf(Wo[src]);
  }
  if (i < 65536) {
    int lay = i >> 14, j = i & 16383;
    { int n = j >> 6, k = j & 63;  ws[W1T_OFF + i] = f2bf(W1[(lay << 14) + (k << 8) + n]); }
    { int n = j >> 8, k = j & 255; ws[W2T_OFF + i] = f2bf(W2[(lay << 14) + (k << 6) + n]); }
  }
  if (i < 5120) {
    int n = i >> 6, k = i & 63;
    ws[WHT_OFF + i] = (n < NV) ? f2bf(Wh[k * NV + n]) : (u16)0;
  }
}

// ---------------- LN stats only (murs = mu*rs, rs) ----------------
__device__ __forceinline__ void ln_stats(const u16 (*src)[72], float* murs_s, float* rs_s, int l) {
  int r = l >> 1, c0 = (l & 1) * 32;
  float s = 0.f, sq = 0.f;
#pragma unroll
  for (int c8 = 0; c8 < 4; ++c8) {
    union { bf16x8 h; u32 u[4]; } w;
    w.h = *(const bf16x8*)&src[r][c0 + 8 * c8];
#pragma unroll
    for (int p = 0; p < 4; ++p) {
      float lo = asf(w.u[p] << 16), hi = asf(w.u[p] & 0xffff0000u);
      s += lo + hi;
      sq = fmaf(lo, lo, sq);
      sq = fmaf(hi, hi, sq);
    }
  }
  s = dpp_add<0xB1>(s);
  sq = dpp_add<0xB1>(sq);
  if (!(l & 1)) {
    float mu = s * 0.015625f;
    float var = fmaf(sq, 0.015625f, -mu * mu);
    float rs = __builtin_amdgcn_rsqf(var + 1e-5f);
    rs_s[r] = rs;
    murs_s[r] = mu * rs;
  }
  __syncthreads();
}

// fragment of LN(xs): row fixed, 8 consecutive cols, g/b applied, packed bf16
__device__ __forceinline__ bf16x8 ln_frag(const u16* src, const float* gp, const float* bp,
                                          float rs, float murs) {
  union { bf16x8 h; u32 u[4]; } in, out;
  in.h = *(const bf16x8*)src;
  f32x4 g0 = *(const f32x4*)gp, g1 = *(const f32x4*)(gp + 4);
  f32x4 b0 = *(const f32x4*)bp, b1 = *(const f32x4*)(bp + 4);
  float ga[8] = {g0[0], g0[1], g0[2], g0[3], g1[0], g1[1], g1[2], g1[3]};
  float ba[8] = {b0[0], b0[1], b0[2], b0[3], b1[0], b1[1], b1[2], b1[3]};
#pragma unroll
  for (int p = 0; p < 4; ++p) {
    float lo = asf(in.u[p] << 16), hi = asf(in.u[p] & 0xffff0000u);
    lo = fmaf(lo, rs, -murs);
    hi = fmaf(hi, rs, -murs);
    out.u[p] = cvtpk(fmaf(lo, ga[2 * p], ba[2 * p]), fmaf(hi, ga[2 * p + 1], ba[2 * p + 1]));
  }
  return out.h;
}

#define BUILD_LN_FRAGS(dst, gbase, bbase)                                      \
  {                                                                            \
    float rs0 = rs_s[m], mm0 = murs_s[m];                                      \
    float rs1 = rs_s[16 + m], mm1 = murs_s[16 + m];                            \
    _Pragma("unroll")                                                          \
    for (int ks = 0; ks < 2; ++ks) {                                           \
      const float* gp = (gbase) + 32 * ks + 8 * g;                             \
      const float* bp = (bbase) + 32 * ks + 8 * g;                             \
      dst[0][ks] = ln_frag(&xs[m][32 * ks + 8 * g], gp, bp, rs0, mm0);         \
      dst[1][ks] = ln_frag(&xs[16 + m][32 * ks + 8 * g], gp, bp, rs1, mm1);    \
    }                                                                          \
  }

// ---------------- fused forward: one wave per sequence ----------------
__global__ __launch_bounds__(64, 3) void fwd_kernel(
    const int* __restrict__ idx, const int* __restrict__ tgt,
    const float* __restrict__ tok_emb, const float* __restrict__ pos_emb,
    const float* __restrict__ bo, const float* __restrict__ ln1g, const float* __restrict__ ln1b,
    const float* __restrict__ ln2g, const float* __restrict__ ln2b,
    const float* __restrict__ b1, const float* __restrict__ b2,
    const float* __restrict__ lnfg, const float* __restrict__ lnfb, const float* __restrict__ bh,
    const u16* __restrict__ ws, float* __restrict__ out, float* __restrict__ loss_acc) {
  __shared__ u16 xs[NT][72];   // residual bf16
  __shared__ u16 tp[NT][72];   // attn-out / FFN h1 chunk
  __shared__ u16 qp[NT][40];   // q (cols 0-15) + K-pad/P (cols 16-31)
  __shared__ u16 kh[NT][40];   // k (cols 16-31 permanently zero)
  __shared__ u16 vt[16][40];   // v transposed [dim][tok]
  __shared__ float murs_s[NT];
  __shared__ float rs_s[NT];

  const int l = threadIdx.x;
  const int m = l & 15, g = l >> 4;
  const int row_g = 4 * g;
  const int seq = blockIdx.x;

  // zero K-pads of qp/kh (cols 16..31, all rows)
  {
    int r = l >> 1, c0 = 16 + (l & 1) * 8;
    u32x2 zz; zz[0] = 0u; zz[1] = 0u;
    *(u32x2*)&qp[r][c0] = zz;
    *(u32x2*)&qp[r][c0 + 4] = zz;
    *(u32x2*)&kh[r][c0] = zz;
    *(u32x2*)&kh[r][c0 + 4] = zz;
  }
  // embedding: 2 lanes per row, 32 cols each, packed writes
  {
    int r = l >> 1, c0 = (l & 1) * 32;
    int t = idx[seq * NT + r];
    const float* te = tok_emb + t * ND + c0;
    const float* pe = pos_emb + r * ND + c0;
#pragma unroll
    for (int q8 = 0; q8 < 4; ++q8) {
      f32x4 a0 = *(const f32x4*)(te + 8 * q8);
      f32x4 a1 = *(const f32x4*)(te + 8 * q8 + 4);
      f32x4 p0 = *(const f32x4*)(pe + 8 * q8);
      f32x4 p1 = *(const f32x4*)(pe + 8 * q8 + 4);
      union { bf16x8 h; u32 u[4]; } o;
      o.u[0] = cvtpk(a0[0] + p0[0], a0[1] + p0[1]);
      o.u[1] = cvtpk(a0[2] + p0[2], a0[3] + p0[3]);
      o.u[2] = cvtpk(a1[0] + p1[0], a1[1] + p1[1]);
      o.u[3] = cvtpk(a1[2] + p1[2], a1[3] + p1[3]);
      *(bf16x8*)&xs[r][c0 + 8 * q8] = o.h;
    }
  }
  __syncthreads();

  for (int lay = 0; lay < NL; ++lay) {
    const u16* wq = ws + WQT_OFF + lay * 4096;
    const u16* wk = ws + WKT_OFF + lay * 4096;
    const u16* wv = ws + WVT_OFF + lay * 4096;
    const u16* wo = ws + WOT_OFF + lay * 4096;
    const u16* w1 = ws + W1T_OFF + lay * 16384;
    const u16* w2 = ws + W2T_OFF + lay * 16384;

    ln_stats(xs, murs_s, rs_s, l);
    bf16x8 a_ls[2][2];
    BUILD_LN_FRAGS(a_ls, ln1g + lay * ND, ln1b + lay * ND)

    // ---- attention, head-unrolled with weight prefetch ----
    bf16x8 qf0, qf1, kf0, kf1, vf0, vf1;
    {
      const u16* p = wq + m * 64 + 8 * g;
      qf0 = *(const bf16x8*)p; qf1 = *(const bf16x8*)(p + 32);
      p = wk + m * 64 + 8 * g;
      kf0 = *(const bf16x8*)p; kf1 = *(const bf16x8*)(p + 32);
      p = wv + m * 64 + 8 * g;
      vf0 = *(const bf16x8*)p; vf1 = *(const bf16x8*)(p + 32);
    }
#pragma unroll
    for (int h = 0; h < NH; ++h) {
      f32x4 qa0 = zero4(), qa1 = zero4(), ka0 = zero4(), ka1 = zero4(), va0 = zero4(), va1 = zero4();
      qa0 = MFMA(a_ls[0][0], qf0, qa0); qa0 = MFMA(a_ls[0][1], qf1, qa0);
      qa1 = MFMA(a_ls[1][0], qf0, qa1); qa1 = MFMA(a_ls[1][1], qf1, qa1);
      ka0 = MFMA(a_ls[0][0], kf0, ka0); ka0 = MFMA(a_ls[0][1], kf1, ka0);
      ka1 = MFMA(a_ls[1][0], kf0, ka1); ka1 = MFMA(a_ls[1][1], kf1, ka1);
      va0 = MFMA(a_ls[0][0], vf0, va0); va0 = MFMA(a_ls[0][1], vf1, va0);
      va1 = MFMA(a_ls[1][0], vf0, va1); va1 = MFMA(a_ls[1][1], vf1, va1);
      if (h < 3) {  // prefetch next head's weights
        const u16* p = wq + (16 * (h + 1) + m) * 64 + 8 * g;
        qf0 = *(const bf16x8*)p; qf1 = *(const bf16x8*)(p + 32);
        p = wk + (16 * (h + 1) + m) * 64 + 8 * g;
        kf0 = *(const bf16x8*)p; kf1 = *(const bf16x8*)(p + 32);
        p = wv + (16 * (h + 1) + m) * 64 + 8 * g;
        vf0 = *(const bf16x8*)p; vf1 = *(const bf16x8*)(p + 32);
      }
      __syncthreads();  // prev head done reading qp/vt
#pragma unroll
      for (int r = 0; r < 4; ++r) {
        qp[row_g + r][m] = f2bf(qa0[r] * 0.125f);       // fold D^-0.5 into q
        qp[16 + row_g + r][m] = f2bf(qa1[r] * 0.125f);
        qp[16 + row_g + r][16 + m] = 0;                 // restore mt1 K-pad (was P)
        kh[row_g + r][m] = f2bf(ka0[r]);
        kh[16 + row_g + r][m] = f2bf(ka1[r]);
      }
      {
        u32x2 w0; w0[0] = cvtpk(va0[0], va0[1]); w0[1] = cvtpk(va0[2], va0[3]);
        *(u32x2*)&vt[m][row_g] = w0;
        u32x2 w1v; w1v[0] = cvtpk(va1[0], va1[1]); w1v[1] = cvtpk(va1[2], va1[3]);
        *(u32x2*)&vt[m][16 + row_g] = w1v;
      }
      __syncthreads();
      // scores (sc[mt0][keys16-31] fully causal-masked -> skipped)
      bf16x8 kb0 = *(const bf16x8*)&kh[m][8 * g];
      bf16x8 kb1 = *(const bf16x8*)&kh[16 + m][8 * g];
      bf16x8 aq0 = *(const bf16x8*)&qp[m][8 * g];
      bf16x8 aq1 = *(const bf16x8*)&qp[16 + m][8 * g];
      f32x4 s00 = zero4(), s10 = zero4(), s11 = zero4();
      s00 = MFMA(aq0, kb0, s00);
      s10 = MFMA(aq1, kb0, s10);
      s11 = MFMA(aq1, kb1, s11);
      // max-free causal softmax; keep e unnormalized, normalize after PV
      float i0[4], i1[4];
#pragma unroll
      for (int r = 0; r < 4; ++r) {
        int tok = row_g + r;
        float e0 = (m > tok) ? 0.f : __expf(s00[r]);
        float sm = red16(e0);
        i0[r] = __builtin_amdgcn_rcpf(sm);
        qp[tok][m] = f2bf(e0);
      }
#pragma unroll
      for (int r = 0; r < 4; ++r) {
        int tok = 16 + row_g + r;
        float e0 = __expf(s10[r]);  // cols 0..15 never masked for rows 16..31
        float e1 = (16 + m > tok) ? 0.f : __expf(s11[r]);
        float sm = red16(e0 + e1);
        i1[r] = __builtin_amdgcn_rcpf(sm);
        qp[tok][m] = f2bf(e0);
        qp[tok][16 + m] = f2bf(e1);
      }
      // PV (wave in-order LDS: reads after writes, same array => ordered)
      bf16x8 vb = *(const bf16x8*)&vt[m][8 * g];
      bf16x8 ap0 = *(const bf16x8*)&qp[m][8 * g];
      bf16x8 ap1 = *(const bf16x8*)&qp[16 + m][8 * g];
      f32x4 o0 = zero4(), o1 = zero4();
      o0 = MFMA(ap0, vb, o0);
      o1 = MFMA(ap1, vb, o1);
#pragma unroll
      for (int r = 0; r < 4; ++r) {
        tp[row_g + r][16 * h + m] = f2bf(o0[r] * i0[r]);
        tp[16 + row_g + r][16 * h + m] = f2bf(o1[r] * i1[r]);
      }
    }
    __syncthreads();

    // ---- Wo projection + bias + residual ----
    {
      bf16x8 wof[8];
#pragma unroll
      for (int nt = 0; nt < 4; ++nt) {
        const u16* p = wo + (16 * nt + m) * 64 + 8 * g;
        wof[2 * nt] = *(const bf16x8*)p;
        wof[2 * nt + 1] = *(const bf16x8*)(p + 32);
      }
      bf16x8 a_t[2][2];
#pragma unroll
      for (int mt = 0; mt < 2; ++mt)
#pragma unroll
        for (int ks = 0; ks < 2; ++ks)
          a_t[mt][ks] = *(const bf16x8*)&tp[16 * mt + m][32 * ks + 8 * g];
      f32x4 acc[2][4];
#pragma unroll
      for (int mt = 0; mt < 2; ++mt)
#pragma unroll
        for (int nt = 0; nt < 4; ++nt) acc[mt][nt] = zero4();
#pragma unroll
      for (int ks = 0; ks < 2; ++ks)
#pragma unroll
        for (int nt = 0; nt < 4; ++nt)
#pragma unroll
          for (int mt = 0; mt < 2; ++mt)
            acc[mt][nt] = MFMA(a_t[mt][ks], wof[2 * nt + ks], acc[mt][nt]);
#pragma unroll
      for (int nt = 0; nt < 4; ++nt) {
        float bon = bo[lay * ND + 16 * nt + m];
#pragma unroll
        for (int mt = 0; mt < 2; ++mt)
#pragma unroll
          for (int r = 0; r < 4; ++r) {
            int tok = 16 * mt + row_g + r, col = 16 * nt + m;
            xs[tok][col] = f2bf(acc[mt][nt][r] + bon + bf2f(xs[tok][col]));
          }
      }
    }
    __syncthreads();

    // ---- FFN ----
    ln_stats(xs, murs_s, rs_s, l);
    bf16x8 a_l2[2][2];
    BUILD_LN_FRAGS(a_l2, ln2g + lay * ND, ln2b + lay * ND)
    f32x4 acc2[2][4];
#pragma unroll
    for (int mt = 0; mt < 2; ++mt)
#pragma unroll
      for (int nt = 0; nt < 4; ++nt) acc2[mt][nt] = zero4();
    bf16x8 w1f[8];
#pragma unroll
    for (int nt = 0; nt < 4; ++nt) {
      const u16* p = w1 + (16 * nt + m) * 64 + 8 * g;
      w1f[2 * nt] = *(const bf16x8*)p;
      w1f[2 * nt + 1] = *(const bf16x8*)(p + 32);
    }
#pragma unroll
    for (int c = 0; c < 4; ++c) {
      f32x4 hc[2][4];
#pragma unroll
      for (int mt = 0; mt < 2; ++mt)
#pragma unroll
        for (int nt = 0; nt < 4; ++nt) hc[mt][nt] = zero4();
#pragma unroll
      for (int ks = 0; ks < 2; ++ks)
#pragma unroll
        for (int nt = 0; nt < 4; ++nt)
#pragma unroll
          for (int mt = 0; mt < 2; ++mt)
            hc[mt][nt] = MFMA(a_l2[mt][ks], w1f[2 * nt + ks], hc[mt][nt]);
      bf16x8 w2f[8];
#pragma unroll
      for (int nt = 0; nt < 4; ++nt) {
        const u16* p = w2 + (16 * nt + m) * NFF + 64 * c + 8 * g;
        w2f[2 * nt] = *(const bf16x8*)p;
        w2f[2 * nt + 1] = *(const bf16x8*)(p + 32);
      }
      __syncthreads();
#pragma unroll
      for (int nt = 0; nt < 4; ++nt) {
        float b1n = b1[lay * NFF + 64 * c + 16 * nt + m];
#pragma unroll
        for (int mt = 0; mt < 2; ++mt)
#pragma unroll
          for (int r = 0; r < 4; ++r)
            tp[16 * mt + row_g + r][16 * nt + m] = f2bf(fmaxf(hc[mt][nt][r] + b1n, 0.f));
      }
      __syncthreads();
      bf16x8 a_h[2][2];
#pragma unroll
      for (int mt = 0; mt < 2; ++mt)
#pragma unroll
        for (int ks = 0; ks < 2; ++ks)
          a_h[mt][ks] = *(const bf16x8*)&tp[16 * mt + m][32 * ks + 8 * g];
      if (c < 3) {  // prefetch next chunk's W1
#pragma unroll
        for (int nt = 0; nt < 4; ++nt) {
          const u16* p = w1 + (64 * (c + 1) + 16 * nt + m) * 64 + 8 * g;
          w1f[2 * nt] = *(const bf16x8*)p;
          w1f[2 * nt + 1] = *(const bf16x8*)(p + 32);
        }
      }
#pragma unroll
      for (int ks = 0; ks < 2; ++ks)
#pragma unroll
        for (int nt = 0; nt < 4; ++nt)
#pragma unroll
          for (int mt = 0; mt < 2; ++mt)
            acc2[mt][nt] = MFMA(a_h[mt][ks], w2f[2 * nt + ks], acc2[mt][nt]);
    }
#pragma unroll
    for (int nt = 0; nt < 4; ++nt) {
      float b2n = b2[lay * ND + 16 * nt + m];
#pragma unroll
      for (int mt = 0; mt < 2; ++mt)
#pragma unroll
        for (int r = 0; r < 4; ++r) {
          int tok = 16 * mt + row_g + r, col = 16 * nt + m;
          xs[tok][col] = f2bf(acc2[mt][nt][r] + b2n + bf2f(xs[tok][col]));
        }
    }
    __syncthreads();
  }

  // ---- final LN + head + logits + loss ----
  ln_stats(xs, murs_s, rs_s, l);
  bf16x8 a_f[2][2];
  BUILD_LN_FRAGS(a_f, lnfg, lnfb)
  bf16x8 whf[10];
#pragma unroll
  for (int nt = 0; nt < 5; ++nt) {
    const u16* p = ws + WHT_OFF + (16 * nt + m) * 64 + 8 * g;
    whf[2 * nt] = *(const bf16x8*)p;
    whf[2 * nt + 1] = *(const bf16x8*)(p + 32);
  }
  f32x4 lg[2][5];
#pragma unroll
  for (int mt = 0; mt < 2; ++mt)
#pragma unroll
    for (int nt = 0; nt < 5; ++nt) lg[mt][nt] = zero4();
#pragma unroll
  for (int ks = 0; ks < 2; ++ks)
#pragma unroll
    for (int nt = 0; nt < 5; ++nt)
#pragma unroll
      for (int mt = 0; mt < 2; ++mt)
        lg[mt][nt] = MFMA(a_f[mt][ks], whf[2 * nt + ks], lg[mt][nt]);
  const int* tgp = tgt + seq * NT;
  float bh0 = bh[m], bh1 = bh[16 + m], bh2v = bh[32 + m], bh3 = bh[48 + m], bh4 = bh[64];
  float lloss = 0.f;
#pragma unroll
  for (int mt = 0; mt < 2; ++mt)
#pragma unroll
    for (int r = 0; r < 4; ++r) {
      int tok = 16 * mt + row_g + r;
      float v0 = lg[mt][0][r] + bh0;
      float v1 = lg[mt][1][r] + bh1;
      float v2 = lg[mt][2][r] + bh2v;
      float v3 = lg[mt][3][r] + bh3;
      float v4 = lg[mt][4][r] + bh4;  // only valid for m==0 (class 64)
      float se = __expf(v0) + __expf(v1) + __expf(v2) + __expf(v3) + ((m == 0) ? __expf(v4) : 0.f);
      se = red16(se);
      float lse = __logf(se);
      int t = tgp[tok];
      float tpv = 0.f;
      tpv += (m == t) ? v0 : 0.f;
      tpv += (16 + m == t) ? v1 : 0.f;
      tpv += (32 + m == t) ? v2 : 0.f;
      tpv += (48 + m == t) ? v3 : 0.f;
      tpv += (m == 0 && t == 64) ? v4 : 0.f;
      float tv = __shfl(tpv, 16 * g + (t & 15));
      if (m == 0) lloss += lse - tv;
      float* ob = out + ((size_t)seq * NT + tok) * NV;
      ob[m] = v0;
      ob[16 + m] = v1;
      ob[32 + m] = v2;
      ob[48 + m] = v3;
      if (m == 0) ob[64] = v4;
    }
  lloss += __shfl_xor(lloss, 16);
  lloss += __shfl_xor(lloss, 32);
  if (l == 0) atomicAdd(loss_acc, lloss);
}

__global__ void finalize_kernel(const float* __restrict__ loss_acc, float* __restrict__ out) {
  if (threadIdx.x == 0 && blockIdx.x == 0)
    out[(size_t)NTOK * NV] = loss_acc[0] * (1.f / (float)NTOK);
}

extern "C" void kernel_launch(void* const* d_in, const int* in_sizes, int n_in,
                              void* d_out, int out_size, void* d_ws, size_t ws_size,
                              hipStream_t stream) {
  const int* idx = (const int*)d_in[0];
  const int* tgt = (const int*)d_in[1];
  const float* tok_emb = (const float*)d_in[2];
  const float* pos_emb = (const float*)d_in[3];
  const float* Wq = (const float*)d_in[4];
  const float* Wk = (const float*)d_in[5];
  const float* Wv = (const float*)d_in[6];
  const float* Wo = (const float*)d_in[7];
  const float* bo = (const float*)d_in[8];
  const float* ln1g = (const float*)d_in[9];
  const float* ln1b = (const float*)d_in[10];
  const float* ln2g = (const float*)d_in[11];
  const float* ln2b = (const float*)d_in[12];
  const float* W1 = (const float*)d_in[13];
  const float* b1 = (const float*)d_in[14];
  const float* W2 = (const float*)d_in[15];
  const float* b2 = (const float*)d_in[16];
  const float* lnfg = (const float*)d_in[17];
  const float* lnfb = (const float*)d_in[18];
  const float* Wh = (const float*)d_in[19];
  const float* bh = (const float*)d_in[20];
  u16* ws = (u16*)d_ws;
  float* loss_acc = (float*)((char*)d_ws + LOSS_BYTE_OFF);
  float* out = (float*)d_out;

  prep_kernel<<<256, 256, 0, stream>>>(Wq, Wk, Wv, Wo, W1, W2, Wh, ws, loss_acc);
  fwd_kernel<<<NSEQ, 64, 0, stream>>>(idx, tgt, tok_emb, pos_emb, bo, ln1g, ln1b, ln2g, ln2b,
                                      b1, b2, lnfg, lnfb, bh, ws, out, loss_acc);
  finalize_kernel<<<1, 64, 0, stream>>>(loss_acc, out);
}